// Round 14
// baseline (850.109 us; speedup 1.0000x reference)
//
#include <hip/hip_runtime.h>
#include <math.h>

// Problem constants: B=32, S=12, N=2048, F=1, H=128, G=64, O=1, P=3
#define NB 32
#define SS 12
#define NN 2048
#define HH 128
#define GG 64
#define PP 3
#define RR (NN*NB)   // 65536 rows, node-major r = n*32 + b

typedef __attribute__((ext_vector_type(8))) _Float16 half8;  // 8 fp16 (4 VGPRs)
typedef __attribute__((ext_vector_type(4))) float f32x4;

__device__ __forceinline__ void glds16(const void* g, const void* l) {
    __builtin_amdgcn_global_load_lds(
        (const __attribute__((address_space(1))) void*)g,
        (__attribute__((address_space(3))) void*)l, 16, 0, 0);
}

// Explicit DMA drain for the legacy 2-phase GEMM body (determinism insurance).
#define DRAIN_STAGING() asm volatile("s_waitcnt vmcnt(0) lgkmcnt(0)" ::: "memory")

// Pipeline primitives (raw barrier, counted waits; rule #18 fences).
#define RAWBAR() __builtin_amdgcn_s_barrier()
#define LGKM0() do { asm volatile("s_waitcnt lgkmcnt(0)" ::: "memory"); \
                     __builtin_amdgcn_sched_barrier(0); } while (0)
#define VMW(n)  do { asm volatile("s_waitcnt vmcnt(" #n ")" ::: "memory"); \
                     __builtin_amdgcn_sched_barrier(0); } while (0)

// ---------------------------------------------------------------------------
// fp32 -> fp16 (RNE), 8 elems/thread
__global__ __launch_bounds__(256) void cvtadj(
    const float* __restrict__ src, _Float16* __restrict__ dst)
{
    size_t i0 = ((size_t)blockIdx.x * 256 + threadIdx.x) * 8;
    float4 v0 = *(const float4*)(src + i0);
    float4 v1 = *(const float4*)(src + i0 + 4);
    union { _Float16 h[8]; uint4 q; } H;
    H.h[0]=(_Float16)v0.x; H.h[1]=(_Float16)v0.y;
    H.h[2]=(_Float16)v0.z; H.h[3]=(_Float16)v0.w;
    H.h[4]=(_Float16)v1.x; H.h[5]=(_Float16)v1.y;
    H.h[6]=(_Float16)v1.z; H.h[7]=(_Float16)v1.w;
    *(uint4*)(dst + i0) = H.q;
}

// Encoder x -> fp16 rows [(t*32+b)][n] from x[b][t][n]. 384 blocks.
__global__ __launch_bounds__(256) void xcvt_enc(
    const float* __restrict__ x, _Float16* __restrict__ dst)
{
    const int row = blockIdx.x;            // t*32 + b
    const int t = row >> 5, b = row & 31;
    const size_t n0 = (size_t)threadIdx.x * 8;
    const float* src = x + ((size_t)b*SS + t)*NN;
    float4 v0 = *(const float4*)(src + n0);
    float4 v1 = *(const float4*)(src + n0 + 4);
    union { _Float16 h[8]; uint4 q; } H;
    H.h[0]=(_Float16)v0.x; H.h[1]=(_Float16)v0.y;
    H.h[2]=(_Float16)v0.z; H.h[3]=(_Float16)v0.w;
    H.h[4]=(_Float16)v1.x; H.h[5]=(_Float16)v1.y;
    H.h[6]=(_Float16)v1.z; H.h[7]=(_Float16)v1.w;
    *(uint4*)(dst + (size_t)row*NN + n0) = H.q;
}

// ---------------------------------------------------------------------------
// Precompute Wc[64][384] = Wg2 @ Wih and bc[384] = bg2 @ Wih + bih.
__global__ __launch_bounds__(256) void wprep(
    const float* __restrict__ Wg2, const float* __restrict__ Wih,
    const float* __restrict__ bih, const float* __restrict__ bg2,
    float* __restrict__ Wc, float* __restrict__ bc)
{
    int idx = blockIdx.x * 256 + threadIdx.x;
    if (idx < GG*384) {
        int g = idx / 384, o = idx % 384;
        float s = 0.f;
        for (int k = 0; k < HH; ++k)
            s = fmaf(Wg2[g*HH + k], Wih[k*384 + o], s);
        Wc[idx] = s;
    } else if (idx < GG*384 + 384) {
        int o = idx - GG*384;
        float s = bih[o];
        for (int k = 0; k < HH; ++k)
            s = fmaf(bg2[k], Wih[k*384 + o], s);
        bc[o] = s;
    }
}

// Wcomb[o][k] fp16 (o=0..383, k=0..191): k<64 -> Wc[k][o], else Whh[k-64][o].
__global__ __launch_bounds__(256) void wprep2(
    const float* __restrict__ Wc, const float* __restrict__ Whh,
    _Float16* __restrict__ Wcomb)
{
    int idx = blockIdx.x * 256 + threadIdx.x;
    if (idx < 384*192) {
        int o = idx / 192, k = idx % 192;
        float v = (k < 64) ? Wc[k*384 + o] : Whh[(k-64)*384 + o];
        Wcomb[idx] = (_Float16)v;
    }
}

// ---------------------------------------------------------------------------
// h1 from ax partials: H[(ty*2048 + c)][n] = fp16(relu(ax[.]*W1[g]+b1[g])),
// c = b*64+g; ax row = col_base + ty*32 + b, summed over 2 split-K partials.
__global__ __launch_bounds__(256) void h1T(
    const float* __restrict__ axpart, int col_base, size_t part_stride,
    const float* __restrict__ Wg1, const float* __restrict__ bg1,
    _Float16* __restrict__ Hh)
{
    const int c = blockIdx.x;
    const int ty = blockIdx.y;
    const int b = c >> 6, g = c & 63;
    const float w1 = Wg1[g], b1 = bg1[g];
    const size_t n0 = (size_t)threadIdx.x * 8;
    const size_t rowoff = (size_t)(col_base + ty*32 + b) * NN + n0;
    float f[8] = {0,0,0,0,0,0,0,0};
#pragma unroll
    for (int p = 0; p < 2; ++p) {
        const float4* q = (const float4*)(axpart + p*part_stride + rowoff);
        float4 v0 = q[0], v1 = q[1];
        f[0]+=v0.x; f[1]+=v0.y; f[2]+=v0.z; f[3]+=v0.w;
        f[4]+=v1.x; f[5]+=v1.y; f[6]+=v1.z; f[7]+=v1.w;
    }
    union { _Float16 h[8]; uint4 q; } H;
#pragma unroll
    for (int k = 0; k < 8; ++k)
        H.h[k] = (_Float16)fmaxf(fmaf(f[k], w1, b1), 0.f);
    *(uint4*)(Hh + ((size_t)ty*2048 + c) * NN + n0) = H.q;
}

// ---------------------------------------------------------------------------
// 256x384 fp16 GEMM, BK=32, 3-deep LDS ring. C = A @ B^T.
// Round-13: mid-tile barriers removed (1 barrier/tile). Round-14: the
// hand-written LGKM0 (lgkmcnt(0) + sched_barrier) before each MFMA cluster
// is ALSO removed — the ds_reads are plain C++ LDS loads, so the compiler
// inserts fine-grained per-consumer lgkmcnt(N) and may interleave ds_read
// with MFMA (coarse drain + schedule pin was the m141 anti-pattern).
// Cross-wave staging safety is carried entirely by VMW(5) ("memory"
// clobber — no LDS read can hoist above it) + the end-of-tile RAWBAR.
__global__ __launch_bounds__(512, 2) void gemm384(
    const _Float16* __restrict__ Ah, const _Float16* __restrict__ Bh,
    _Float16* __restrict__ C, int ldc, int kchunk)
{
    __shared__ __align__(16) _Float16 As[3][8192];    // 16 chunks x 512 each
    __shared__ __align__(16) _Float16 Bs[3][12288];   // 24 chunks x 512 each
    const int tid = threadIdx.x;
    const int w = tid >> 6, lane = tid & 63;
    const int lm = lane & 15, lq = lane >> 4;
    const int wm = w >> 2, wn = w & 3;                // 2M x 4N wave grid
    // XCD transpose: wg%8 -> m-row (A-panel resident per XCD L2)
    const int wg = blockIdx.x;
    const int m0 = (wg & 7) * 256, n0 = (wg >> 3) * 384;
    const int NT = kchunk >> 5;                        // K-tiles of 32

    f32x4 acc[8][6];
#pragma unroll
    for (int i = 0; i < 8; ++i)
#pragma unroll
        for (int j = 0; j < 6; ++j) acc[i][j] = (f32x4){0.f,0.f,0.f,0.f};

    // stage A (16 chunks, 2/wave) / B (24 chunks, 3/wave) of K-tile T
    auto stA = [&](int buf, int T) {
#pragma unroll
        for (int c = 0; c < 2; ++c) {
            int chunk = w*2 + c;                       // m-tile index
            glds16(Ah + (size_t)(m0 + chunk*16 + lm)*2048 + T*32 + lq*8,
                   &As[buf][chunk*512]);
        }
    };
    auto stB = [&](int buf, int T) {
#pragma unroll
        for (int c = 0; c < 3; ++c) {
            int chunk = w*3 + c;                       // n-tile index
            glds16(Bh + (size_t)(n0 + chunk*16 + lm)*2048 + T*32 + lq*8,
                   &Bs[buf][chunk*512]);
        }
    };

    // prologue: tiles 0 and 1 staged; tile0 landed, tile1's 5 in flight
    stA(0, 0); stB(0, 0);
    stA(1, 1); stB(1, 1);
    VMW(5);
    RAWBAR();

    int cur = 0;
    for (int T = 0; T < NT; ++T) {
        const int b2 = (cur >= 1) ? cur - 1 : 2;       // (cur+2)%3
        half8 af[4], bf[6];
        // ---- phase 0: mh=0 rows, all 6 n-tiles --------------------------
#pragma unroll
        for (int i = 0; i < 4; ++i)
            af[i] = *(const half8*)&As[cur][(wm*8 + i)*512 + lane*8];
#pragma unroll
        for (int j = 0; j < 6; ++j)
            bf[j] = *(const half8*)&Bs[cur][(wn*6 + j)*512 + lane*8];
        if (T + 2 < NT) stA(b2, T + 2);
        __builtin_amdgcn_s_setprio(1);
#pragma unroll
        for (int i = 0; i < 4; ++i)
#pragma unroll
            for (int j = 0; j < 6; ++j)
                acc[i][j] = __builtin_amdgcn_mfma_f32_16x16x32_f16(
                    af[i], bf[j], acc[i][j], 0, 0, 0);
        __builtin_amdgcn_s_setprio(0);
        // ---- phase 1: mh=1 rows, reuse bf (no mid-tile barriers) --------
#pragma unroll
        for (int i = 0; i < 4; ++i)
            af[i] = *(const half8*)&As[cur][(wm*8 + 4 + i)*512 + lane*8];
        if (T + 2 < NT) stB(b2, T + 2);
        __builtin_amdgcn_s_setprio(1);
#pragma unroll
        for (int i = 0; i < 4; ++i)
#pragma unroll
            for (int j = 0; j < 6; ++j)
                acc[4 + i][j] = __builtin_amdgcn_mfma_f32_16x16x32_f16(
                    af[i], bf[j], acc[4 + i][j], 0, 0, 0);
        __builtin_amdgcn_s_setprio(0);
        if (T + 2 < NT)      { VMW(5); }   // next tile landed, T+2 in flight
        else if (T + 1 < NT) { VMW(0); }   // drain for the final tile
        RAWBAR();                          // the one sync point per tile
        cur = (cur < 2) ? cur + 1 : 0;
    }
    // epilogue: fp16 C; rows m0 + wm*128 + i*16 + lq*4 + reg,
    //           cols n0 + wn*96 + j*16 + lm
#pragma unroll
    for (int i = 0; i < 8; ++i) {
        int row = m0 + wm*128 + i*16 + lq*4;
#pragma unroll
        for (int j = 0; j < 6; ++j) {
            int col = n0 + wn*96 + j*16 + lm;
            _Float16* cp = C + (size_t)row*ldc + col;
            cp[0*(size_t)ldc] = (_Float16)acc[i][j][0];
            cp[1*(size_t)ldc] = (_Float16)acc[i][j][1];
            cp[2*(size_t)ldc] = (_Float16)acc[i][j][2];
            cp[3*(size_t)ldc] = (_Float16)acc[i][j][3];
        }
    }
}

// ---------------------------------------------------------------------------
// Legacy 128x128 2-phase MFMA GEMM body (kept for the small decoder GEMMs).
#define GEMM_BODY                                                              \
    __shared__ __align__(16) _Float16 As[8192];  /* 16 tiles x (16m x 32k) */  \
    __shared__ __align__(16) _Float16 Bs[8192];                                \
    const int tid  = threadIdx.x;                                              \
    const int wv   = tid >> 6, lane = tid & 63;                                \
    const int lm   = lane & 15, lq = lane >> 4;                                \
    const int m0   = blockIdx.y * 128;                                         \
    const int n0   = blockIdx.x * 128;                                         \
    const int wm   = wv >> 1, wn = wv & 1;                                     \
    f32x4 acc[4][4];                                                           \
    _Pragma("unroll")                                                          \
    for (int i = 0; i < 4; ++i)                                                \
        _Pragma("unroll")                                                      \
        for (int j = 0; j < 4; ++j) acc[i][j] = (f32x4){0.f,0.f,0.f,0.f};      \
    const int kbeg = blockIdx.z * kchunk, kend = kbeg + kchunk;                \
    for (int k0 = kbeg; k0 < kend; k0 += 64) {                                 \
        _Pragma("unroll")                                                      \
        for (int t = 0; t < 4; ++t) {                                          \
            int tt = wv*4 + t;                                                 \
            int rt = tt >> 1, kt = tt & 1;                                     \
            glds16(Ah + (size_t)(m0 + rt*16 + lm)*2048 + k0 + kt*32 + lq*8,    \
                   &As[tt*512]);                                               \
            glds16(Bh + (size_t)(n0 + rt*16 + lm)*2048 + k0 + kt*32 + lq*8,    \
                   &Bs[tt*512]);                                               \
        }                                                                      \
        DRAIN_STAGING();                                                       \
        __syncthreads();                                                       \
        _Pragma("unroll")                                                      \
        for (int ks = 0; ks < 2; ++ks) {                                       \
            half8 af[4], bf[4];                                                \
            _Pragma("unroll")                                                  \
            for (int i = 0; i < 4; ++i) {                                      \
                af[i] = *(const half8*)&As[((wm*4 + i)*2 + ks)*512 + lane*8];  \
                bf[i] = *(const half8*)&Bs[((wn*4 + i)*2 + ks)*512 + lane*8];  \
            }                                                                  \
            _Pragma("unroll")                                                  \
            for (int i = 0; i < 4; ++i)                                        \
                _Pragma("unroll")                                              \
                for (int j = 0; j < 4; ++j)                                    \
                    acc[i][j] = __builtin_amdgcn_mfma_f32_16x16x32_f16(        \
                        af[i], bf[j], acc[i][j], 0, 0, 0);                     \
        }                                                                      \
        __syncthreads();                                                       \
    }

// fp32 partial epilogue: C[row*2048 + col] + split-K offset (decoder z).
__global__ __launch_bounds__(256) void gemm_mfma_p(
    const _Float16* __restrict__ Ah, const _Float16* __restrict__ Bh,
    float* __restrict__ Cbase, int kchunk, size_t partstride)
{
    float* C = Cbase + (size_t)blockIdx.z * partstride;
    GEMM_BODY
#pragma unroll
    for (int i = 0; i < 4; ++i) {
        int row = m0 + wm*64 + i*16 + lq*4;
#pragma unroll
        for (int j = 0; j < 4; ++j) {
            int col = n0 + wn*64 + j*16 + lm;
            float* cp = C + (size_t)row*2048 + col;
            cp[0*2048] = acc[i][j][0];
            cp[1*2048] = acc[i][j][1];
            cp[2*2048] = acc[i][j][2];
            cp[3*2048] = acc[i][j][3];
        }
    }
}

// Transposed fp32 epilogue: C[col*2048 + row], float4 per (i,j). ax = adj@X^T.
__global__ __launch_bounds__(256) void gemm_mfma_T(
    const _Float16* __restrict__ Ah, const _Float16* __restrict__ Bh,
    float* __restrict__ Cbase, int kchunk, size_t partstride)
{
    float* C = Cbase + (size_t)blockIdx.z * partstride;
    GEMM_BODY
#pragma unroll
    for (int i = 0; i < 4; ++i) {
        int row = m0 + wm*64 + i*16 + lq*4;
#pragma unroll
        for (int j = 0; j < 4; ++j) {
            int col = n0 + wn*64 + j*16 + lm;
            float4 v = {acc[i][j][0], acc[i][j][1], acc[i][j][2], acc[i][j][3]};
            *(float4*)(C + (size_t)col*2048 + row) = v;
        }
    }
}

// zsum: Z16[i] = fp16(p0[i] + p1[i]), 8 elems/thread, 2048 blocks.
__global__ __launch_bounds__(256) void zsum(
    const float* __restrict__ p0, const float* __restrict__ p1,
    _Float16* __restrict__ z)
{
    size_t i0 = ((size_t)blockIdx.x * 256 + threadIdx.x) * 8;
    float4 a0 = *(const float4*)(p0 + i0), a1 = *(const float4*)(p0 + i0 + 4);
    float4 b0 = *(const float4*)(p1 + i0), b1 = *(const float4*)(p1 + i0 + 4);
    union { _Float16 h[8]; uint4 q; } H;
    H.h[0]=(_Float16)(a0.x+b0.x); H.h[1]=(_Float16)(a0.y+b0.y);
    H.h[2]=(_Float16)(a0.z+b0.z); H.h[3]=(_Float16)(a0.w+b0.w);
    H.h[4]=(_Float16)(a1.x+b1.x); H.h[5]=(_Float16)(a1.y+b1.y);
    H.h[6]=(_Float16)(a1.z+b1.z); H.h[7]=(_Float16)(a1.w+b1.w);
    *(uint4*)(z + i0) = H.q;
}

// ---------------------------------------------------------------------------
// Fast activations: rcp/exp based. Round-9/10 verified numerically free —
// absmax stayed bit-identical at 2.384e-07 with these in both gate kernels.
__device__ __forceinline__ float sigmoidf_(float x) {
    return __builtin_amdgcn_rcpf(1.f + __expf(-x));
}
__device__ __forceinline__ float tanhf_(float x) {
    float xc = fmaxf(-15.f, fminf(15.f, x));
    float e = __expf(-2.f * xc);          // e^{-2x}, finite on [-15,15]
    return (1.f - e) * __builtin_amdgcn_rcpf(1.f + e);
}

// gatemm2: W-stationary streaming gate kernel (round-7, ~43 us/dispatch).
// Kept for the 2 decoder steps only.
template<int HZERO>
__global__ __launch_bounds__(512, 2) void gatemm2(
    const _Float16* __restrict__ Z16, int ldz, int zoff,
    const _Float16* __restrict__ Wcomb,
    const float* __restrict__ bc, const float* __restrict__ bhh,
    _Float16* __restrict__ H16)
{
    const int tid = threadIdx.x;
    const int w = tid >> 6, lane = tid & 63;
    const int lm = lane & 15, lq = lane >> 4;
    const int o0 = w*16 + lq*4;

    half8 wr[6], wz[6], wn[6];
#pragma unroll
    for (int c = 0; c < 6; ++c) {
        wr[c] = *(const half8*)&Wcomb[(size_t)((w     )*16 + lm)*192 + c*32 + lq*8];
        wz[c] = *(const half8*)&Wcomb[(size_t)((8 + w )*16 + lm)*192 + c*32 + lq*8];
        wn[c] = *(const half8*)&Wcomb[(size_t)((16 + w)*16 + lm)*192 + c*32 + lq*8];
    }
    float br_[4], bz_[4], bnx_[4], bnh_[4];
#pragma unroll
    for (int reg = 0; reg < 4; ++reg) {
        int o = o0 + reg;
        br_[reg]  = bc[o]     + bhh[o];
        bz_[reg]  = bc[o+128] + bhh[o+128];
        bnx_[reg] = bc[o+256];
        bnh_[reg] = bhh[o+256];
    }

    const int g0 = blockIdx.x * 8;

    auto zp_of = [&](int g, int rt2) {
        int r = g*32 + rt2*16 + lm;
        return (const half8*)&Z16[(size_t)(r >> 5)*ldz + zoff + (r & 31)*64 + lq*8];
    };

    half8 zA[2][2], zB[2][2];
#pragma unroll
    for (int rt2 = 0; rt2 < 2; ++rt2) {
        const half8* zp = zp_of(g0, rt2);
        zA[rt2][0] = zp[0]; zA[rt2][1] = zp[4];
    }

    union HU { ushort4 q; _Float16 h[4]; };

#pragma unroll
    for (int i = 0; i < 8; ++i) {
        const int g = g0 + i;
        const int r0 = g*32;

        half8 hf[2][4];
        HU holdu[2];
        if (!HZERO) {
#pragma unroll
            for (int rt2 = 0; rt2 < 2; ++rt2) {
                const _Float16* hp = &H16[(size_t)(r0 + rt2*16 + lm)*128];
#pragma unroll
                for (int c4 = 0; c4 < 4; ++c4)
                    hf[rt2][c4] = *(const half8*)(hp + c4*32 + lq*8);
                holdu[rt2].q = *(const ushort4*)(hp + o0);
            }
        }

        f32x4 ar[2], az[2], anx[2], anh[2];
#pragma unroll
        for (int rt2 = 0; rt2 < 2; ++rt2) {
            ar[rt2]  = (f32x4){0.f,0.f,0.f,0.f};
            az[rt2]  = (f32x4){0.f,0.f,0.f,0.f};
            anx[rt2] = (f32x4){0.f,0.f,0.f,0.f};
            anh[rt2] = (f32x4){0.f,0.f,0.f,0.f};
        }
#pragma unroll
        for (int rt2 = 0; rt2 < 2; ++rt2) {
#pragma unroll
            for (int c2 = 0; c2 < 2; ++c2) {
                half8 rf = (i & 1) ? zB[rt2][c2] : zA[rt2][c2];
                ar[rt2]  = __builtin_amdgcn_mfma_f32_16x16x32_f16(
                    wr[c2], rf, ar[rt2], 0, 0, 0);
                az[rt2]  = __builtin_amdgcn_mfma_f32_16x16x32_f16(
                    wz[c2], rf, az[rt2], 0, 0, 0);
                anx[rt2] = __builtin_amdgcn_mfma_f32_16x16x32_f16(
                    wn[c2], rf, anx[rt2], 0, 0, 0);
            }
            if (!HZERO) {
#pragma unroll
                for (int c4 = 0; c4 < 4; ++c4) {
                    ar[rt2]  = __builtin_amdgcn_mfma_f32_16x16x32_f16(
                        wr[2+c4], hf[rt2][c4], ar[rt2], 0, 0, 0);
                    az[rt2]  = __builtin_amdgcn_mfma_f32_16x16x32_f16(
                        wz[2+c4], hf[rt2][c4], az[rt2], 0, 0, 0);
                    anh[rt2] = __builtin_amdgcn_mfma_f32_16x16x32_f16(
                        wn[2+c4], hf[rt2][c4], anh[rt2], 0, 0, 0);
                }
            }
        }
        if (i + 1 < 8) {
#pragma unroll
            for (int rt2 = 0; rt2 < 2; ++rt2) {
                const half8* zp = zp_of(g + 1, rt2);
                if (i & 1) { zA[rt2][0] = zp[0]; zA[rt2][1] = zp[4]; }
                else       { zB[rt2][0] = zp[0]; zB[rt2][1] = zp[4]; }
            }
        }
        if (!HZERO) {
            RAWBAR();
            __builtin_amdgcn_sched_barrier(0);
        }

#pragma unroll
        for (int rt2 = 0; rt2 < 2; ++rt2) {
            const int r = r0 + rt2*16 + lm;
            HU outu;
#pragma unroll
            for (int reg = 0; reg < 4; ++reg) {
                float hold = HZERO ? 0.f : (float)holdu[rt2].h[reg];
                float rg = sigmoidf_(ar[rt2][reg] + br_[reg]);
                float zg = sigmoidf_(az[rt2][reg] + bz_[reg]);
                float ng = tanhf_(anx[rt2][reg] + bnx_[reg]
                                  + rg*(anh[rt2][reg] + bnh_[reg]));
                outu.h[reg] = (_Float16)((1.f - zg)*ng + zg*hold);
            }
            *(ushort4*)&H16[(size_t)r*128 + o0] = outu.q;
        }
    }
}

// ---------------------------------------------------------------------------
// grufuse v3 (round-10 proven): ALL 12 encoder GRU steps in ONE kernel;
// H never leaves chip. Occupancy lever closed (rounds 11/12): ~88-reg
// footprint caps at 2 waves/SIMD; (512,4)/(1024,*) spill. W frags
// stationary in VGPRs; Z register-prefetched 1 step ahead across raw
// barriers; hold = lane's own previous output; double-buffered Hl,
// one barrier/step; fast rcp/exp activations (bit-identical verified).
__global__ __launch_bounds__(512, 2) void grufuse(
    const _Float16* __restrict__ Z16,
    const _Float16* __restrict__ Wcomb,
    const float* __restrict__ bc, const float* __restrict__ bhh,
    _Float16* __restrict__ H16)
{
    __shared__ __align__(16) _Float16 Hl[8192];   // 2 bufs x 32 rows x 128
    const int tid = threadIdx.x;
    const int w = tid >> 6, lane = tid & 63;
    const int lm = lane & 15, lq = lane >> 4;
    const int o0 = w*16 + lq*4;
    const int blk = blockIdx.x;

    // stationary W fragments
    half8 wr[6], wz[6], wn[6];
#pragma unroll
    for (int c = 0; c < 6; ++c) {
        wr[c] = *(const half8*)&Wcomb[(size_t)((w     )*16 + lm)*192 + c*32 + lq*8];
        wz[c] = *(const half8*)&Wcomb[(size_t)((8 + w )*16 + lm)*192 + c*32 + lq*8];
        wn[c] = *(const half8*)&Wcomb[(size_t)((16 + w)*16 + lm)*192 + c*32 + lq*8];
    }
    float br_[4], bz_[4], bnx_[4], bnh_[4];
#pragma unroll
    for (int reg = 0; reg < 4; ++reg) {
        int o = o0 + reg;
        br_[reg]  = bc[o]     + bhh[o];
        bz_[reg]  = bc[o+128] + bhh[o+128];
        bnx_[reg] = bc[o+256];
        bnh_[reg] = bhh[o+256];
    }

    // addressing: local row lr = rt2*16 + lm; byte offsets within one 8 KB
    // buffer (buf base added per step): swizzle ^((lr&7)<<4)
    int zrow[2], hrd[2], hmsk[2], hwr[2];
#pragma unroll
    for (int rt2 = 0; rt2 < 2; ++rt2) {
        const int lr = rt2*16 + lm;
        zrow[rt2] = blk*24576 + lr*64 + lq*8;      // + t*2048 + c2*32
        hrd[rt2]  = lr*256 + lq*16;                // + c4*64, then ^hmsk
        hmsk[rt2] = (lr & 7) << 4;
        hwr[rt2]  = (lr*256 + o0*2) ^ hmsk[rt2];
    }

    union HU { ushort4 q; _Float16 h[4]; };
    HU hold[2];
    hold[0].q = (ushort4){0,0,0,0};
    hold[1].q = (ushort4){0,0,0,0};

    half8 zA[2][2], zB[2][2];
#pragma unroll
    for (int rt2 = 0; rt2 < 2; ++rt2)
#pragma unroll
        for (int c2 = 0; c2 < 2; ++c2) {
            zA[rt2][c2] = *(const half8*)&Z16[(size_t)(zrow[rt2] + c2*32)];
            zB[rt2][c2] = *(const half8*)&Z16[(size_t)(zrow[rt2] + 2048 + c2*32)];
        }

    // ---- step 0: z-only, hold = 0, write h0 to LDS buf 0 ----
    {
        f32x4 ar[2], az[2], anx[2];
#pragma unroll
        for (int rt2 = 0; rt2 < 2; ++rt2) {
            ar[rt2] = (f32x4){0.f,0.f,0.f,0.f};
            az[rt2] = (f32x4){0.f,0.f,0.f,0.f};
            anx[rt2] = (f32x4){0.f,0.f,0.f,0.f};
#pragma unroll
            for (int c2 = 0; c2 < 2; ++c2) {
                ar[rt2]  = __builtin_amdgcn_mfma_f32_16x16x32_f16(
                    wr[c2], zA[rt2][c2], ar[rt2], 0, 0, 0);
                az[rt2]  = __builtin_amdgcn_mfma_f32_16x16x32_f16(
                    wz[c2], zA[rt2][c2], az[rt2], 0, 0, 0);
                anx[rt2] = __builtin_amdgcn_mfma_f32_16x16x32_f16(
                    wn[c2], zA[rt2][c2], anx[rt2], 0, 0, 0);
            }
        }
#pragma unroll
        for (int rt2 = 0; rt2 < 2; ++rt2) {
            HU outu;
#pragma unroll
            for (int reg = 0; reg < 4; ++reg) {
                float rg = sigmoidf_(ar[rt2][reg] + br_[reg]);
                float zg = sigmoidf_(az[rt2][reg] + bz_[reg]);
                float ng = tanhf_(anx[rt2][reg] + bnx_[reg] + rg*bnh_[reg]);
                outu.h[reg] = (_Float16)((1.f - zg)*ng);
            }
            hold[rt2] = outu;
            *(ushort4*)((char*)Hl + hwr[rt2]) = outu.q;   // buf 0
        }
        LGKM0();
        RAWBAR();
    }

    // ---- steps 1..11: read buf (t&1)^1, write buf t&1 (double-buffer,
    // one barrier per step) ----
#pragma unroll
    for (int t = 1; t < SS; ++t) {
        const int rb = ((t & 1) ^ 1) * 8192;   // holds h_{t-1}
        const int wb = (t & 1) * 8192;         // will hold h_t
        half8 hf[2][4];
#pragma unroll
        for (int rt2 = 0; rt2 < 2; ++rt2)
#pragma unroll
            for (int c4 = 0; c4 < 4; ++c4)
                hf[rt2][c4] = *(const half8*)((const char*)Hl + rb
                    + ((hrd[rt2] + c4*64) ^ hmsk[rt2]));

        f32x4 ar[2], az[2], anx[2], anh[2];
#pragma unroll
        for (int rt2 = 0; rt2 < 2; ++rt2) {
            ar[rt2]  = (f32x4){0.f,0.f,0.f,0.f};
            az[rt2]  = (f32x4){0.f,0.f,0.f,0.f};
            anx[rt2] = (f32x4){0.f,0.f,0.f,0.f};
            anh[rt2] = (f32x4){0.f,0.f,0.f,0.f};
#pragma unroll
            for (int c2 = 0; c2 < 2; ++c2) {
                half8 rf = (t & 1) ? zB[rt2][c2] : zA[rt2][c2];
                ar[rt2]  = __builtin_amdgcn_mfma_f32_16x16x32_f16(
                    wr[c2], rf, ar[rt2], 0, 0, 0);
                az[rt2]  = __builtin_amdgcn_mfma_f32_16x16x32_f16(
                    wz[c2], rf, az[rt2], 0, 0, 0);
                anx[rt2] = __builtin_amdgcn_mfma_f32_16x16x32_f16(
                    wn[c2], rf, anx[rt2], 0, 0, 0);
            }
#pragma unroll
            for (int c4 = 0; c4 < 4; ++c4) {
                ar[rt2]  = __builtin_amdgcn_mfma_f32_16x16x32_f16(
                    wr[2+c4], hf[rt2][c4], ar[rt2], 0, 0, 0);
                az[rt2]  = __builtin_amdgcn_mfma_f32_16x16x32_f16(
                    wz[2+c4], hf[rt2][c4], az[rt2], 0, 0, 0);
                anh[rt2] = __builtin_amdgcn_mfma_f32_16x16x32_f16(
                    wn[2+c4], hf[rt2][c4], anh[rt2], 0, 0, 0);
            }
        }
        // prefetch z for step t+1 (registers; rides across the barrier)
        if (t + 1 < SS) {
#pragma unroll
            for (int rt2 = 0; rt2 < 2; ++rt2)
#pragma unroll
                for (int c2 = 0; c2 < 2; ++c2) {
                    const half8* zp = (const half8*)
                        &Z16[(size_t)(zrow[rt2] + (t+1)*2048 + c2*32)];
                    if (t & 1) zA[rt2][c2] = *zp;
                    else       zB[rt2][c2] = *zp;
                }
        }

#pragma unroll
        for (int rt2 = 0; rt2 < 2; ++rt2) {
            HU outu;
#pragma unroll
            for (int reg = 0; reg < 4; ++reg) {
                float hv = (float)hold[rt2].h[reg];
                float rg = sigmoidf_(ar[rt2][reg] + br_[reg]);
                float zg = sigmoidf_(az[rt2][reg] + bz_[reg]);
                float ng = tanhf_(anx[rt2][reg] + bnx_[reg]
                                  + rg*(anh[rt2][reg] + bnh_[reg]));
                outu.h[reg] = (_Float16)((1.f - zg)*ng + zg*hv);
            }
            hold[rt2] = outu;
            if (t < SS-1)
                *(ushort4*)((char*)Hl + wb + hwr[rt2]) = outu.q;
        }
        if (t < SS-1) {
            LGKM0();     // ds_writes visible
            RAWBAR();    // one barrier per step (write-buf != read-buf)
        }
    }

    // final: h_12 to global (once)
#pragma unroll
    for (int rt2 = 0; rt2 < 2; ++rt2)
        *(ushort4*)&H16[(size_t)(blk*32 + rt2*16 + lm)*128 + o0] = hold[rt2].q;
}

// ---------------------------------------------------------------------------
// fck: s = h16[r] . W_fc + b_fc ; writes d_out[b][p][n] fp32 AND the decoder's
// next-step X row Xdh[b][n] fp16.
__global__ __launch_bounds__(256) void fck(
    const _Float16* __restrict__ h,
    const float* __restrict__ Wfc, const float* __restrict__ bfc,
    float* __restrict__ out_p,
    _Float16* __restrict__ Xdh)
{
    int w = (blockIdx.x * 256 + threadIdx.x) >> 6;
    int lane = threadIdx.x & 63;
    const _Float16* hr = h + (size_t)w*HH + lane*2;
    const float2* wf = (const float2*)Wfc;
    float2 b2 = wf[lane];
    float s = (float)hr[0]*b2.x + (float)hr[1]*b2.y;
#pragma unroll
    for (int off = 32; off; off >>= 1) s += __shfl_xor(s, off);
    if (lane == 0) {
        s += bfc[0];
        int n = w >> 5, b = w & 31;
        out_p[(size_t)b*(PP*NN) + n] = s;
        Xdh[(size_t)b*NN + n] = (_Float16)s;
    }
}

// ---------------------------------------------------------------------------
extern "C" void kernel_launch(void* const* d_in, const int* in_sizes, int n_in,
                              void* d_out, int out_size, void* d_ws, size_t ws_size,
                              hipStream_t stream)
{
    const float* x    = (const float*)d_in[0];
    const float* adj  = (const float*)d_in[1];
    const float* Wg1  = (const float*)d_in[2];
    const float* bg1  = (const float*)d_in[3];
    const float* Wg2  = (const float*)d_in[4];
    const float* bg2  = (const float*)d_in[5];
    const float* Wih  = (const float*)d_in[6];
    const float* Whh  = (const float*)d_in[7];
    const float* bih  = (const float*)d_in[8];
    const float* bhh  = (const float*)d_in[9];
    const float* Wfc  = (const float*)d_in[10];
    const float* bfc  = (const float*)d_in[11];

    float* ws = (float*)d_ws;
    float* Wc   = ws;                              // 64*384
    float* bc   = Wc + GG*384;                     // 1024 (384 used)
    float* AXe  = bc + 1024;                       // 2 partials x 384 x 2048
    float* AXd  = AXe + (size_t)2*384*NN;          // 2 partials x 128 x 2048
    _Float16* Ah    = (_Float16*)(AXd + (size_t)2*128*NN);  // 2048x2048 (8 MB)
    _Float16* Xeh   = Ah    + (size_t)NN*NN;       // 384 x 2048
    _Float16* Xdh   = Xeh   + (size_t)384*NN;      // 128 x 2048
    _Float16* Hgh   = Xdh   + (size_t)128*NN;      // 12288 x 2048 (48 MB)
    _Float16* Z16   = Hgh   + (size_t)12288*NN;    // 2048 x 24576 (96 MB)
    _Float16* H16   = Z16   + (size_t)NN*24576;    // RR*HH fp16 (16 MB) master
    _Float16* Wcomb = H16   + (size_t)RR*HH;       // 384*192
    // decoder split-K fp32 partials live in Hgh rows 2048.. (unused then)
    float* Zp = (float*)(Hgh + (size_t)2048*NN);   // 2 x 2048x2048 fp32
    // total ws use ~178 MiB

    // Determinism insurance: zero the entire used workspace every call so
    // each call's output is a pure function of the inputs (the harness
    // re-poisons d_ws between verify and timing; post-timing check is a
    // consistency tripwire at 3.1x verify absmax).
    {
        size_t used = (size_t)((char*)(Wcomb + (size_t)384*192) - (char*)d_ws);
        hipMemsetAsync(d_ws, 0, used, stream);
    }

    cvtadj<<<2048, 256, 0, stream>>>(adj, Ah);
    wprep<<<98, 256, 0, stream>>>(Wg2, Wih, bih, bg2, Wc, bc);
    wprep2<<<288, 256, 0, stream>>>(Wc, Whh, Wcomb);
    xcvt_enc<<<384, 256, 0, stream>>>(x, Xeh);
    // encoder ax = adj @ Xe^T, all 12 steps (split-K 2, transposed fp32 C)
    gemm_mfma_T<<<dim3(3, 16, 2), 256, 0, stream>>>(
        Ah, Xeh, AXe, 1024, (size_t)384*NN);

    float* outp = (float*)d_out;

    // encoder z for all 12 steps: 2 groups of 6 (N=12288 cols each),
    // 256x384 BK=32 GEMM: 256 blocks = exactly 1 block/CU, 64 K-tiles
    for (int g = 0; g < 2; ++g) {
        h1T<<<dim3(NN, 6), 256, 0, stream>>>(
            AXe, g*192, (size_t)384*NN, Wg1, bg1, Hgh);
        gemm384<<<256, 512, 0, stream>>>(
            Ah, Hgh, Z16 + (size_t)g*12288, 24576, 2048);
    }
    // ALL 12 encoder GRU steps fused; H stays in LDS/registers
    grufuse<<<RR/32, 512, 0, stream>>>(Z16, Wcomb, bc, bhh, H16);

    // decoder
    for (int p = 0; p < PP; ++p) {
        fck<<<RR/4, 256, 0, stream>>>(H16, Wfc, bfc, outp + (size_t)p*NN, Xdh);
        if (p < PP-1) {
            gemm_mfma_T<<<dim3(1, 16, 2), 256, 0, stream>>>(
                Ah, Xdh, AXd, 1024, (size_t)128*NN);
            h1T<<<dim3(NN, 1), 256, 0, stream>>>(
                AXd, 0, (size_t)128*NN, Wg1, bg1, Hgh);
            // decoder z: split-K 2 (512 blocks, 2/CU) + fp16 combine
            gemm_mfma_p<<<dim3(16, 16, 2), 256, 0, stream>>>(
                Ah, Hgh, Zp, 1024, (size_t)NN*NN);
            zsum<<<2048, 256, 0, stream>>>(Zp, Zp + (size_t)NN*NN, Z16);
            gatemm2<0><<<256, 512, 0, stream>>>(
                Z16, 2048, 0, Wcomb, bc, bhh, H16);
        }
    }
}

// Round 15
// 842.707 us; speedup vs baseline: 1.0088x; 1.0088x over previous
//
#include <hip/hip_runtime.h>
#include <math.h>

// Problem constants: B=32, S=12, N=2048, F=1, H=128, G=64, O=1, P=3
#define NB 32
#define SS 12
#define NN 2048
#define HH 128
#define GG 64
#define PP 3
#define RR (NN*NB)   // 65536 rows, node-major r = n*32 + b

typedef __attribute__((ext_vector_type(8))) _Float16 half8;  // 8 fp16 (4 VGPRs)
typedef __attribute__((ext_vector_type(4))) float f32x4;

__device__ __forceinline__ void glds16(const void* g, const void* l) {
    __builtin_amdgcn_global_load_lds(
        (const __attribute__((address_space(1))) void*)g,
        (__attribute__((address_space(3))) void*)l, 16, 0, 0);
}

// Explicit DMA drain for the legacy 2-phase GEMM body (determinism insurance).
#define DRAIN_STAGING() asm volatile("s_waitcnt vmcnt(0) lgkmcnt(0)" ::: "memory")

// Pipeline primitives (raw barrier, counted waits; rule #18 fences).
#define RAWBAR() __builtin_amdgcn_s_barrier()
#define LGKM0() do { asm volatile("s_waitcnt lgkmcnt(0)" ::: "memory"); \
                     __builtin_amdgcn_sched_barrier(0); } while (0)
#define VMW(n)  do { asm volatile("s_waitcnt vmcnt(" #n ")" ::: "memory"); \
                     __builtin_amdgcn_sched_barrier(0); } while (0)

// ---------------------------------------------------------------------------
// fp32 -> fp16 (RNE), 8 elems/thread
__global__ __launch_bounds__(256) void cvtadj(
    const float* __restrict__ src, _Float16* __restrict__ dst)
{
    size_t i0 = ((size_t)blockIdx.x * 256 + threadIdx.x) * 8;
    float4 v0 = *(const float4*)(src + i0);
    float4 v1 = *(const float4*)(src + i0 + 4);
    union { _Float16 h[8]; uint4 q; } H;
    H.h[0]=(_Float16)v0.x; H.h[1]=(_Float16)v0.y;
    H.h[2]=(_Float16)v0.z; H.h[3]=(_Float16)v0.w;
    H.h[4]=(_Float16)v1.x; H.h[5]=(_Float16)v1.y;
    H.h[6]=(_Float16)v1.z; H.h[7]=(_Float16)v1.w;
    *(uint4*)(dst + i0) = H.q;
}

// Encoder x -> fp16 rows [(t*32+b)][n] from x[b][t][n]. 384 blocks.
__global__ __launch_bounds__(256) void xcvt_enc(
    const float* __restrict__ x, _Float16* __restrict__ dst)
{
    const int row = blockIdx.x;            // t*32 + b
    const int t = row >> 5, b = row & 31;
    const size_t n0 = (size_t)threadIdx.x * 8;
    const float* src = x + ((size_t)b*SS + t)*NN;
    float4 v0 = *(const float4*)(src + n0);
    float4 v1 = *(const float4*)(src + n0 + 4);
    union { _Float16 h[8]; uint4 q; } H;
    H.h[0]=(_Float16)v0.x; H.h[1]=(_Float16)v0.y;
    H.h[2]=(_Float16)v0.z; H.h[3]=(_Float16)v0.w;
    H.h[4]=(_Float16)v1.x; H.h[5]=(_Float16)v1.y;
    H.h[6]=(_Float16)v1.z; H.h[7]=(_Float16)v1.w;
    *(uint4*)(dst + (size_t)row*NN + n0) = H.q;
}

// ---------------------------------------------------------------------------
// Precompute Wc[64][384] = Wg2 @ Wih and bc[384] = bg2 @ Wih + bih.
__global__ __launch_bounds__(256) void wprep(
    const float* __restrict__ Wg2, const float* __restrict__ Wih,
    const float* __restrict__ bih, const float* __restrict__ bg2,
    float* __restrict__ Wc, float* __restrict__ bc)
{
    int idx = blockIdx.x * 256 + threadIdx.x;
    if (idx < GG*384) {
        int g = idx / 384, o = idx % 384;
        float s = 0.f;
        for (int k = 0; k < HH; ++k)
            s = fmaf(Wg2[g*HH + k], Wih[k*384 + o], s);
        Wc[idx] = s;
    } else if (idx < GG*384 + 384) {
        int o = idx - GG*384;
        float s = bih[o];
        for (int k = 0; k < HH; ++k)
            s = fmaf(bg2[k], Wih[k*384 + o], s);
        bc[o] = s;
    }
}

// Wcomb[o][k] fp16 (o=0..383, k=0..191): k<64 -> Wc[k][o], else Whh[k-64][o].
__global__ __launch_bounds__(256) void wprep2(
    const float* __restrict__ Wc, const float* __restrict__ Whh,
    _Float16* __restrict__ Wcomb)
{
    int idx = blockIdx.x * 256 + threadIdx.x;
    if (idx < 384*192) {
        int o = idx / 192, k = idx % 192;
        float v = (k < 64) ? Wc[k*384 + o] : Whh[(k-64)*384 + o];
        Wcomb[idx] = (_Float16)v;
    }
}

// ---------------------------------------------------------------------------
// h1 from ax partials: H[(ty*2048 + c)][n] = fp16(relu(ax[.]*W1[g]+b1[g])),
// c = b*64+g; ax row = col_base + ty*32 + b, summed over np partials.
__global__ __launch_bounds__(256) void h1T(
    const float* __restrict__ axpart, int col_base, size_t part_stride,
    const float* __restrict__ Wg1, const float* __restrict__ bg1,
    _Float16* __restrict__ Hh, int np)
{
    const int c = blockIdx.x;
    const int ty = blockIdx.y;
    const int b = c >> 6, g = c & 63;
    const float w1 = Wg1[g], b1 = bg1[g];
    const size_t n0 = (size_t)threadIdx.x * 8;
    const size_t rowoff = (size_t)(col_base + ty*32 + b) * NN + n0;
    float f[8] = {0,0,0,0,0,0,0,0};
    for (int p = 0; p < np; ++p) {
        const float4* q = (const float4*)(axpart + p*part_stride + rowoff);
        float4 v0 = q[0], v1 = q[1];
        f[0]+=v0.x; f[1]+=v0.y; f[2]+=v0.z; f[3]+=v0.w;
        f[4]+=v1.x; f[5]+=v1.y; f[6]+=v1.z; f[7]+=v1.w;
    }
    union { _Float16 h[8]; uint4 q; } H;
#pragma unroll
    for (int k = 0; k < 8; ++k)
        H.h[k] = (_Float16)fmaxf(fmaf(f[k], w1, b1), 0.f);
    *(uint4*)(Hh + ((size_t)ty*2048 + c) * NN + n0) = H.q;
}

// ---------------------------------------------------------------------------
// 256x384 fp16 GEMM, BK=32, 3-deep LDS ring. C = A @ B^T.
// Rounds 13/14: 1 barrier/tile, no hand waitcnt before MFMA (compiler emits
// fine-grained lgkmcnt). Cross-wave staging safety = VMW(5) + end barrier.
__global__ __launch_bounds__(512, 2) void gemm384(
    const _Float16* __restrict__ Ah, const _Float16* __restrict__ Bh,
    _Float16* __restrict__ C, int ldc, int kchunk)
{
    __shared__ __align__(16) _Float16 As[3][8192];    // 16 chunks x 512 each
    __shared__ __align__(16) _Float16 Bs[3][12288];   // 24 chunks x 512 each
    const int tid = threadIdx.x;
    const int w = tid >> 6, lane = tid & 63;
    const int lm = lane & 15, lq = lane >> 4;
    const int wm = w >> 2, wn = w & 3;                // 2M x 4N wave grid
    const int wg = blockIdx.x;
    const int m0 = (wg & 7) * 256, n0 = (wg >> 3) * 384;
    const int NT = kchunk >> 5;                        // K-tiles of 32

    f32x4 acc[8][6];
#pragma unroll
    for (int i = 0; i < 8; ++i)
#pragma unroll
        for (int j = 0; j < 6; ++j) acc[i][j] = (f32x4){0.f,0.f,0.f,0.f};

    auto stA = [&](int buf, int T) {
#pragma unroll
        for (int c = 0; c < 2; ++c) {
            int chunk = w*2 + c;
            glds16(Ah + (size_t)(m0 + chunk*16 + lm)*2048 + T*32 + lq*8,
                   &As[buf][chunk*512]);
        }
    };
    auto stB = [&](int buf, int T) {
#pragma unroll
        for (int c = 0; c < 3; ++c) {
            int chunk = w*3 + c;
            glds16(Bh + (size_t)(n0 + chunk*16 + lm)*2048 + T*32 + lq*8,
                   &Bs[buf][chunk*512]);
        }
    };

    stA(0, 0); stB(0, 0);
    stA(1, 1); stB(1, 1);
    VMW(5);
    RAWBAR();

    int cur = 0;
    for (int T = 0; T < NT; ++T) {
        const int b2 = (cur >= 1) ? cur - 1 : 2;       // (cur+2)%3
        half8 af[4], bf[6];
#pragma unroll
        for (int i = 0; i < 4; ++i)
            af[i] = *(const half8*)&As[cur][(wm*8 + i)*512 + lane*8];
#pragma unroll
        for (int j = 0; j < 6; ++j)
            bf[j] = *(const half8*)&Bs[cur][(wn*6 + j)*512 + lane*8];
        if (T + 2 < NT) stA(b2, T + 2);
        __builtin_amdgcn_s_setprio(1);
#pragma unroll
        for (int i = 0; i < 4; ++i)
#pragma unroll
            for (int j = 0; j < 6; ++j)
                acc[i][j] = __builtin_amdgcn_mfma_f32_16x16x32_f16(
                    af[i], bf[j], acc[i][j], 0, 0, 0);
        __builtin_amdgcn_s_setprio(0);
#pragma unroll
        for (int i = 0; i < 4; ++i)
            af[i] = *(const half8*)&As[cur][(wm*8 + 4 + i)*512 + lane*8];
        if (T + 2 < NT) stB(b2, T + 2);
        __builtin_amdgcn_s_setprio(1);
#pragma unroll
        for (int i = 0; i < 4; ++i)
#pragma unroll
            for (int j = 0; j < 6; ++j)
                acc[4 + i][j] = __builtin_amdgcn_mfma_f32_16x16x32_f16(
                    af[i], bf[j], acc[4 + i][j], 0, 0, 0);
        __builtin_amdgcn_s_setprio(0);
        if (T + 2 < NT)      { VMW(5); }
        else if (T + 1 < NT) { VMW(0); }
        RAWBAR();
        cur = (cur < 2) ? cur + 1 : 0;
    }
#pragma unroll
    for (int i = 0; i < 8; ++i) {
        int row = m0 + wm*128 + i*16 + lq*4;
#pragma unroll
        for (int j = 0; j < 6; ++j) {
            int col = n0 + wn*96 + j*16 + lm;
            _Float16* cp = C + (size_t)row*ldc + col;
            cp[0*(size_t)ldc] = (_Float16)acc[i][j][0];
            cp[1*(size_t)ldc] = (_Float16)acc[i][j][1];
            cp[2*(size_t)ldc] = (_Float16)acc[i][j][2];
            cp[3*(size_t)ldc] = (_Float16)acc[i][j][3];
        }
    }
}

// ---------------------------------------------------------------------------
// gemmdz: decoder z-GEMM. 128x128 tile, BK=32, 3-deep ring (clone of the
// round-13-proven gemm384 pipeline: no drains, VMW(4), 1 barrier/tile),
// 4 waves (2x2), single K=2048 pass, fp16 C written DIRECTLY into Z16 —
// replaces the legacy split-K gemm_mfma_p (full vmcnt(0) drain per K-step)
// + zsum combine pass. Grid 16x16 = 256 blocks.
__global__ __launch_bounds__(256, 2) void gemmdz(
    const _Float16* __restrict__ Ah, const _Float16* __restrict__ Bh,
    _Float16* __restrict__ C, int ldc)
{
    __shared__ __align__(16) _Float16 As[3][4096];    // 8 chunks x 512 each
    __shared__ __align__(16) _Float16 Bs[3][4096];
    const int tid = threadIdx.x;
    const int w = tid >> 6, lane = tid & 63;
    const int lm = lane & 15, lq = lane >> 4;
    const int wm = w >> 1, wn = w & 1;                // 2M x 2N wave grid
    const int m0 = blockIdx.y * 128, n0 = blockIdx.x * 128;
    const int NT = 2048 >> 5;                          // 64 K-tiles of 32

    f32x4 acc[4][4];
#pragma unroll
    for (int i = 0; i < 4; ++i)
#pragma unroll
        for (int j = 0; j < 4; ++j) acc[i][j] = (f32x4){0.f,0.f,0.f,0.f};

    auto stA = [&](int buf, int T) {
#pragma unroll
        for (int c = 0; c < 2; ++c) {
            int chunk = w*2 + c;                       // 8 m-subtiles
            glds16(Ah + (size_t)(m0 + chunk*16 + lm)*2048 + T*32 + lq*8,
                   &As[buf][chunk*512]);
        }
    };
    auto stB = [&](int buf, int T) {
#pragma unroll
        for (int c = 0; c < 2; ++c) {
            int chunk = w*2 + c;
            glds16(Bh + (size_t)(n0 + chunk*16 + lm)*2048 + T*32 + lq*8,
                   &Bs[buf][chunk*512]);
        }
    };

    stA(0, 0); stB(0, 0);
    stA(1, 1); stB(1, 1);
    VMW(4);                       // tile0's 4 landed, tile1's 4 in flight
    RAWBAR();

    int cur = 0;
    for (int T = 0; T < NT; ++T) {
        const int b2 = (cur >= 1) ? cur - 1 : 2;       // (cur+2)%3
        half8 af[2], bf[4];
        // phase 0: m-subtiles 0,1 of this wave + all 4 n-subtiles
#pragma unroll
        for (int i = 0; i < 2; ++i)
            af[i] = *(const half8*)&As[cur][(wm*4 + i)*512 + lane*8];
#pragma unroll
        for (int j = 0; j < 4; ++j)
            bf[j] = *(const half8*)&Bs[cur][(wn*4 + j)*512 + lane*8];
        if (T + 2 < NT) stA(b2, T + 2);
        __builtin_amdgcn_s_setprio(1);
#pragma unroll
        for (int i = 0; i < 2; ++i)
#pragma unroll
            for (int j = 0; j < 4; ++j)
                acc[i][j] = __builtin_amdgcn_mfma_f32_16x16x32_f16(
                    af[i], bf[j], acc[i][j], 0, 0, 0);
        __builtin_amdgcn_s_setprio(0);
        // phase 1: m-subtiles 2,3; reuse bf
#pragma unroll
        for (int i = 0; i < 2; ++i)
            af[i] = *(const half8*)&As[cur][(wm*4 + 2 + i)*512 + lane*8];
        if (T + 2 < NT) stB(b2, T + 2);
        __builtin_amdgcn_s_setprio(1);
#pragma unroll
        for (int i = 0; i < 2; ++i)
#pragma unroll
            for (int j = 0; j < 4; ++j)
                acc[2 + i][j] = __builtin_amdgcn_mfma_f32_16x16x32_f16(
                    af[i], bf[j], acc[2 + i][j], 0, 0, 0);
        __builtin_amdgcn_s_setprio(0);
        if (T + 2 < NT)      { VMW(4); }
        else if (T + 1 < NT) { VMW(0); }
        RAWBAR();
        cur = (cur < 2) ? cur + 1 : 0;
    }
#pragma unroll
    for (int i = 0; i < 4; ++i) {
        int row = m0 + wm*64 + i*16 + lq*4;
#pragma unroll
        for (int j = 0; j < 4; ++j) {
            int col = n0 + wn*64 + j*16 + lm;
            _Float16* cp = C + (size_t)row*ldc + col;
            cp[0*(size_t)ldc] = (_Float16)acc[i][j][0];
            cp[1*(size_t)ldc] = (_Float16)acc[i][j][1];
            cp[2*(size_t)ldc] = (_Float16)acc[i][j][2];
            cp[3*(size_t)ldc] = (_Float16)acc[i][j][3];
        }
    }
}

// ---------------------------------------------------------------------------
// Legacy 128x128 2-phase MFMA GEMM body (kept for gemm_mfma_T).
#define GEMM_BODY                                                              \
    __shared__ __align__(16) _Float16 As[8192];  /* 16 tiles x (16m x 32k) */  \
    __shared__ __align__(16) _Float16 Bs[8192];                                \
    const int tid  = threadIdx.x;                                              \
    const int wv   = tid >> 6, lane = tid & 63;                                \
    const int lm   = lane & 15, lq = lane >> 4;                                \
    const int m0   = blockIdx.y * 128;                                         \
    const int n0   = blockIdx.x * 128;                                         \
    const int wm   = wv >> 1, wn = wv & 1;                                     \
    f32x4 acc[4][4];                                                           \
    _Pragma("unroll")                                                          \
    for (int i = 0; i < 4; ++i)                                                \
        _Pragma("unroll")                                                      \
        for (int j = 0; j < 4; ++j) acc[i][j] = (f32x4){0.f,0.f,0.f,0.f};      \
    const int kbeg = blockIdx.z * kchunk, kend = kbeg + kchunk;                \
    for (int k0 = kbeg; k0 < kend; k0 += 64) {                                 \
        _Pragma("unroll")                                                      \
        for (int t = 0; t < 4; ++t) {                                          \
            int tt = wv*4 + t;                                                 \
            int rt = tt >> 1, kt = tt & 1;                                     \
            glds16(Ah + (size_t)(m0 + rt*16 + lm)*2048 + k0 + kt*32 + lq*8,    \
                   &As[tt*512]);                                               \
            glds16(Bh + (size_t)(n0 + rt*16 + lm)*2048 + k0 + kt*32 + lq*8,    \
                   &Bs[tt*512]);                                               \
        }                                                                      \
        DRAIN_STAGING();                                                       \
        __syncthreads();                                                       \
        _Pragma("unroll")                                                      \
        for (int ks = 0; ks < 2; ++ks) {                                       \
            half8 af[4], bf[4];                                                \
            _Pragma("unroll")                                                  \
            for (int i = 0; i < 4; ++i) {                                      \
                af[i] = *(const half8*)&As[((wm*4 + i)*2 + ks)*512 + lane*8];  \
                bf[i] = *(const half8*)&Bs[((wn*4 + i)*2 + ks)*512 + lane*8];  \
            }                                                                  \
            _Pragma("unroll")                                                  \
            for (int i = 0; i < 4; ++i)                                        \
                _Pragma("unroll")                                              \
                for (int j = 0; j < 4; ++j)                                    \
                    acc[i][j] = __builtin_amdgcn_mfma_f32_16x16x32_f16(        \
                        af[i], bf[j], acc[i][j], 0, 0, 0);                     \
        }                                                                      \
        __syncthreads();                                                       \
    }

// Transposed fp32 epilogue: C[col*2048 + row], float4 per (i,j). ax = adj@X^T.
__global__ __launch_bounds__(256) void gemm_mfma_T(
    const _Float16* __restrict__ Ah, const _Float16* __restrict__ Bh,
    float* __restrict__ Cbase, int kchunk, size_t partstride)
{
    float* C = Cbase + (size_t)blockIdx.z * partstride;
    GEMM_BODY
#pragma unroll
    for (int i = 0; i < 4; ++i) {
        int row = m0 + wm*64 + i*16 + lq*4;
#pragma unroll
        for (int j = 0; j < 4; ++j) {
            int col = n0 + wn*64 + j*16 + lm;
            float4 v = {acc[i][j][0], acc[i][j][1], acc[i][j][2], acc[i][j][3]};
            *(float4*)(C + (size_t)col*2048 + row) = v;
        }
    }
}

// ---------------------------------------------------------------------------
// Fast activations: rcp/exp based (verified bit-identical rounds 9/10).
__device__ __forceinline__ float sigmoidf_(float x) {
    return __builtin_amdgcn_rcpf(1.f + __expf(-x));
}
__device__ __forceinline__ float tanhf_(float x) {
    float xc = fmaxf(-15.f, fminf(15.f, x));
    float e = __expf(-2.f * xc);          // e^{-2x}, finite on [-15,15]
    return (1.f - e) * __builtin_amdgcn_rcpf(1.f + e);
}

// gatemm2: W-stationary streaming gate kernel (round-7, ~43 us/dispatch).
// Kept for the 2 decoder steps only.
template<int HZERO>
__global__ __launch_bounds__(512, 2) void gatemm2(
    const _Float16* __restrict__ Z16, int ldz, int zoff,
    const _Float16* __restrict__ Wcomb,
    const float* __restrict__ bc, const float* __restrict__ bhh,
    _Float16* __restrict__ H16)
{
    const int tid = threadIdx.x;
    const int w = tid >> 6, lane = tid & 63;
    const int lm = lane & 15, lq = lane >> 4;
    const int o0 = w*16 + lq*4;

    half8 wr[6], wz[6], wn[6];
#pragma unroll
    for (int c = 0; c < 6; ++c) {
        wr[c] = *(const half8*)&Wcomb[(size_t)((w     )*16 + lm)*192 + c*32 + lq*8];
        wz[c] = *(const half8*)&Wcomb[(size_t)((8 + w )*16 + lm)*192 + c*32 + lq*8];
        wn[c] = *(const half8*)&Wcomb[(size_t)((16 + w)*16 + lm)*192 + c*32 + lq*8];
    }
    float br_[4], bz_[4], bnx_[4], bnh_[4];
#pragma unroll
    for (int reg = 0; reg < 4; ++reg) {
        int o = o0 + reg;
        br_[reg]  = bc[o]     + bhh[o];
        bz_[reg]  = bc[o+128] + bhh[o+128];
        bnx_[reg] = bc[o+256];
        bnh_[reg] = bhh[o+256];
    }

    const int g0 = blockIdx.x * 8;

    auto zp_of = [&](int g, int rt2) {
        int r = g*32 + rt2*16 + lm;
        return (const half8*)&Z16[(size_t)(r >> 5)*ldz + zoff + (r & 31)*64 + lq*8];
    };

    half8 zA[2][2], zB[2][2];
#pragma unroll
    for (int rt2 = 0; rt2 < 2; ++rt2) {
        const half8* zp = zp_of(g0, rt2);
        zA[rt2][0] = zp[0]; zA[rt2][1] = zp[4];
    }

    union HU { ushort4 q; _Float16 h[4]; };

#pragma unroll
    for (int i = 0; i < 8; ++i) {
        const int g = g0 + i;
        const int r0 = g*32;

        half8 hf[2][4];
        HU holdu[2];
        if (!HZERO) {
#pragma unroll
            for (int rt2 = 0; rt2 < 2; ++rt2) {
                const _Float16* hp = &H16[(size_t)(r0 + rt2*16 + lm)*128];
#pragma unroll
                for (int c4 = 0; c4 < 4; ++c4)
                    hf[rt2][c4] = *(const half8*)(hp + c4*32 + lq*8);
                holdu[rt2].q = *(const ushort4*)(hp + o0);
            }
        }

        f32x4 ar[2], az[2], anx[2], anh[2];
#pragma unroll
        for (int rt2 = 0; rt2 < 2; ++rt2) {
            ar[rt2]  = (f32x4){0.f,0.f,0.f,0.f};
            az[rt2]  = (f32x4){0.f,0.f,0.f,0.f};
            anx[rt2] = (f32x4){0.f,0.f,0.f,0.f};
            anh[rt2] = (f32x4){0.f,0.f,0.f,0.f};
        }
#pragma unroll
        for (int rt2 = 0; rt2 < 2; ++rt2) {
#pragma unroll
            for (int c2 = 0; c2 < 2; ++c2) {
                half8 rf = (i & 1) ? zB[rt2][c2] : zA[rt2][c2];
                ar[rt2]  = __builtin_amdgcn_mfma_f32_16x16x32_f16(
                    wr[c2], rf, ar[rt2], 0, 0, 0);
                az[rt2]  = __builtin_amdgcn_mfma_f32_16x16x32_f16(
                    wz[c2], rf, az[rt2], 0, 0, 0);
                anx[rt2] = __builtin_amdgcn_mfma_f32_16x16x32_f16(
                    wn[c2], rf, anx[rt2], 0, 0, 0);
            }
            if (!HZERO) {
#pragma unroll
                for (int c4 = 0; c4 < 4; ++c4) {
                    ar[rt2]  = __builtin_amdgcn_mfma_f32_16x16x32_f16(
                        wr[2+c4], hf[rt2][c4], ar[rt2], 0, 0, 0);
                    az[rt2]  = __builtin_amdgcn_mfma_f32_16x16x32_f16(
                        wz[2+c4], hf[rt2][c4], az[rt2], 0, 0, 0);
                    anh[rt2] = __builtin_amdgcn_mfma_f32_16x16x32_f16(
                        wn[2+c4], hf[rt2][c4], anh[rt2], 0, 0, 0);
                }
            }
        }
        if (i + 1 < 8) {
#pragma unroll
            for (int rt2 = 0; rt2 < 2; ++rt2) {
                const half8* zp = zp_of(g + 1, rt2);
                if (i & 1) { zA[rt2][0] = zp[0]; zA[rt2][1] = zp[4]; }
                else       { zB[rt2][0] = zp[0]; zB[rt2][1] = zp[4]; }
            }
        }
        if (!HZERO) {
            RAWBAR();
            __builtin_amdgcn_sched_barrier(0);
        }

#pragma unroll
        for (int rt2 = 0; rt2 < 2; ++rt2) {
            const int r = r0 + rt2*16 + lm;
            HU outu;
#pragma unroll
            for (int reg = 0; reg < 4; ++reg) {
                float hold = HZERO ? 0.f : (float)holdu[rt2].h[reg];
                float rg = sigmoidf_(ar[rt2][reg] + br_[reg]);
                float zg = sigmoidf_(az[rt2][reg] + bz_[reg]);
                float ng = tanhf_(anx[rt2][reg] + bnx_[reg]
                                  + rg*(anh[rt2][reg] + bnh_[reg]));
                outu.h[reg] = (_Float16)((1.f - zg)*ng + zg*hold);
            }
            *(ushort4*)&H16[(size_t)r*128 + o0] = outu.q;
        }
    }
}

// ---------------------------------------------------------------------------
// grufuse v3 (round-10 proven): ALL 12 encoder GRU steps in ONE kernel;
// H never leaves chip. Occupancy lever closed (rounds 11/12): ~88-reg
// footprint caps at 2 waves/SIMD; higher-occupancy variants spill.
__global__ __launch_bounds__(512, 2) void grufuse(
    const _Float16* __restrict__ Z16,
    const _Float16* __restrict__ Wcomb,
    const float* __restrict__ bc, const float* __restrict__ bhh,
    _Float16* __restrict__ H16)
{
    __shared__ __align__(16) _Float16 Hl[8192];   // 2 bufs x 32 rows x 128
    const int tid = threadIdx.x;
    const int w = tid >> 6, lane = tid & 63;
    const int lm = lane & 15, lq = lane >> 4;
    const int o0 = w*16 + lq*4;
    const int blk = blockIdx.x;

    half8 wr[6], wz[6], wn[6];
#pragma unroll
    for (int c = 0; c < 6; ++c) {
        wr[c] = *(const half8*)&Wcomb[(size_t)((w     )*16 + lm)*192 + c*32 + lq*8];
        wz[c] = *(const half8*)&Wcomb[(size_t)((8 + w )*16 + lm)*192 + c*32 + lq*8];
        wn[c] = *(const half8*)&Wcomb[(size_t)((16 + w)*16 + lm)*192 + c*32 + lq*8];
    }
    float br_[4], bz_[4], bnx_[4], bnh_[4];
#pragma unroll
    for (int reg = 0; reg < 4; ++reg) {
        int o = o0 + reg;
        br_[reg]  = bc[o]     + bhh[o];
        bz_[reg]  = bc[o+128] + bhh[o+128];
        bnx_[reg] = bc[o+256];
        bnh_[reg] = bhh[o+256];
    }

    int zrow[2], hrd[2], hmsk[2], hwr[2];
#pragma unroll
    for (int rt2 = 0; rt2 < 2; ++rt2) {
        const int lr = rt2*16 + lm;
        zrow[rt2] = blk*24576 + lr*64 + lq*8;      // + t*2048 + c2*32
        hrd[rt2]  = lr*256 + lq*16;                // + c4*64, then ^hmsk
        hmsk[rt2] = (lr & 7) << 4;
        hwr[rt2]  = (lr*256 + o0*2) ^ hmsk[rt2];
    }

    union HU { ushort4 q; _Float16 h[4]; };
    HU hold[2];
    hold[0].q = (ushort4){0,0,0,0};
    hold[1].q = (ushort4){0,0,0,0};

    half8 zA[2][2], zB[2][2];
#pragma unroll
    for (int rt2 = 0; rt2 < 2; ++rt2)
#pragma unroll
        for (int c2 = 0; c2 < 2; ++c2) {
            zA[rt2][c2] = *(const half8*)&Z16[(size_t)(zrow[rt2] + c2*32)];
            zB[rt2][c2] = *(const half8*)&Z16[(size_t)(zrow[rt2] + 2048 + c2*32)];
        }

    // ---- step 0 ----
    {
        f32x4 ar[2], az[2], anx[2];
#pragma unroll
        for (int rt2 = 0; rt2 < 2; ++rt2) {
            ar[rt2] = (f32x4){0.f,0.f,0.f,0.f};
            az[rt2] = (f32x4){0.f,0.f,0.f,0.f};
            anx[rt2] = (f32x4){0.f,0.f,0.f,0.f};
#pragma unroll
            for (int c2 = 0; c2 < 2; ++c2) {
                ar[rt2]  = __builtin_amdgcn_mfma_f32_16x16x32_f16(
                    wr[c2], zA[rt2][c2], ar[rt2], 0, 0, 0);
                az[rt2]  = __builtin_amdgcn_mfma_f32_16x16x32_f16(
                    wz[c2], zA[rt2][c2], az[rt2], 0, 0, 0);
                anx[rt2] = __builtin_amdgcn_mfma_f32_16x16x32_f16(
                    wn[c2], zA[rt2][c2], anx[rt2], 0, 0, 0);
            }
        }
#pragma unroll
        for (int rt2 = 0; rt2 < 2; ++rt2) {
            HU outu;
#pragma unroll
            for (int reg = 0; reg < 4; ++reg) {
                float rg = sigmoidf_(ar[rt2][reg] + br_[reg]);
                float zg = sigmoidf_(az[rt2][reg] + bz_[reg]);
                float ng = tanhf_(anx[rt2][reg] + bnx_[reg] + rg*bnh_[reg]);
                outu.h[reg] = (_Float16)((1.f - zg)*ng);
            }
            hold[rt2] = outu;
            *(ushort4*)((char*)Hl + hwr[rt2]) = outu.q;   // buf 0
        }
        LGKM0();
        RAWBAR();
    }

    // ---- steps 1..11 ----
#pragma unroll
    for (int t = 1; t < SS; ++t) {
        const int rb = ((t & 1) ^ 1) * 8192;
        const int wb = (t & 1) * 8192;
        half8 hf[2][4];
#pragma unroll
        for (int rt2 = 0; rt2 < 2; ++rt2)
#pragma unroll
            for (int c4 = 0; c4 < 4; ++c4)
                hf[rt2][c4] = *(const half8*)((const char*)Hl + rb
                    + ((hrd[rt2] + c4*64) ^ hmsk[rt2]));

        f32x4 ar[2], az[2], anx[2], anh[2];
#pragma unroll
        for (int rt2 = 0; rt2 < 2; ++rt2) {
            ar[rt2]  = (f32x4){0.f,0.f,0.f,0.f};
            az[rt2]  = (f32x4){0.f,0.f,0.f,0.f};
            anx[rt2] = (f32x4){0.f,0.f,0.f,0.f};
            anh[rt2] = (f32x4){0.f,0.f,0.f,0.f};
#pragma unroll
            for (int c2 = 0; c2 < 2; ++c2) {
                half8 rf = (t & 1) ? zB[rt2][c2] : zA[rt2][c2];
                ar[rt2]  = __builtin_amdgcn_mfma_f32_16x16x32_f16(
                    wr[c2], rf, ar[rt2], 0, 0, 0);
                az[rt2]  = __builtin_amdgcn_mfma_f32_16x16x32_f16(
                    wz[c2], rf, az[rt2], 0, 0, 0);
                anx[rt2] = __builtin_amdgcn_mfma_f32_16x16x32_f16(
                    wn[c2], rf, anx[rt2], 0, 0, 0);
            }
#pragma unroll
            for (int c4 = 0; c4 < 4; ++c4) {
                ar[rt2]  = __builtin_amdgcn_mfma_f32_16x16x32_f16(
                    wr[2+c4], hf[rt2][c4], ar[rt2], 0, 0, 0);
                az[rt2]  = __builtin_amdgcn_mfma_f32_16x16x32_f16(
                    wz[2+c4], hf[rt2][c4], az[rt2], 0, 0, 0);
                anh[rt2] = __builtin_amdgcn_mfma_f32_16x16x32_f16(
                    wn[2+c4], hf[rt2][c4], anh[rt2], 0, 0, 0);
            }
        }
        if (t + 1 < SS) {
#pragma unroll
            for (int rt2 = 0; rt2 < 2; ++rt2)
#pragma unroll
                for (int c2 = 0; c2 < 2; ++c2) {
                    const half8* zp = (const half8*)
                        &Z16[(size_t)(zrow[rt2] + (t+1)*2048 + c2*32)];
                    if (t & 1) zA[rt2][c2] = *zp;
                    else       zB[rt2][c2] = *zp;
                }
        }

#pragma unroll
        for (int rt2 = 0; rt2 < 2; ++rt2) {
            HU outu;
#pragma unroll
            for (int reg = 0; reg < 4; ++reg) {
                float hv = (float)hold[rt2].h[reg];
                float rg = sigmoidf_(ar[rt2][reg] + br_[reg]);
                float zg = sigmoidf_(az[rt2][reg] + bz_[reg]);
                float ng = tanhf_(anx[rt2][reg] + bnx_[reg]
                                  + rg*(anh[rt2][reg] + bnh_[reg]));
                outu.h[reg] = (_Float16)((1.f - zg)*ng + zg*hv);
            }
            hold[rt2] = outu;
            if (t < SS-1)
                *(ushort4*)((char*)Hl + wb + hwr[rt2]) = outu.q;
        }
        if (t < SS-1) {
            LGKM0();
            RAWBAR();
        }
    }

#pragma unroll
    for (int rt2 = 0; rt2 < 2; ++rt2)
        *(ushort4*)&H16[(size_t)(blk*32 + rt2*16 + lm)*128 + o0] = hold[rt2].q;
}

// ---------------------------------------------------------------------------
// fck: s = h16[r] . W_fc + b_fc ; writes d_out[b][p][n] fp32 AND the decoder's
// next-step X row Xdh[b][n] fp16.
__global__ __launch_bounds__(256) void fck(
    const _Float16* __restrict__ h,
    const float* __restrict__ Wfc, const float* __restrict__ bfc,
    float* __restrict__ out_p,
    _Float16* __restrict__ Xdh)
{
    int w = (blockIdx.x * 256 + threadIdx.x) >> 6;
    int lane = threadIdx.x & 63;
    const _Float16* hr = h + (size_t)w*HH + lane*2;
    const float2* wf = (const float2*)Wfc;
    float2 b2 = wf[lane];
    float s = (float)hr[0]*b2.x + (float)hr[1]*b2.y;
#pragma unroll
    for (int off = 32; off; off >>= 1) s += __shfl_xor(s, off);
    if (lane == 0) {
        s += bfc[0];
        int n = w >> 5, b = w & 31;
        out_p[(size_t)b*(PP*NN) + n] = s;
        Xdh[(size_t)b*NN + n] = (_Float16)s;
    }
}

// ---------------------------------------------------------------------------
extern "C" void kernel_launch(void* const* d_in, const int* in_sizes, int n_in,
                              void* d_out, int out_size, void* d_ws, size_t ws_size,
                              hipStream_t stream)
{
    const float* x    = (const float*)d_in[0];
    const float* adj  = (const float*)d_in[1];
    const float* Wg1  = (const float*)d_in[2];
    const float* bg1  = (const float*)d_in[3];
    const float* Wg2  = (const float*)d_in[4];
    const float* bg2  = (const float*)d_in[5];
    const float* Wih  = (const float*)d_in[6];
    const float* Whh  = (const float*)d_in[7];
    const float* bih  = (const float*)d_in[8];
    const float* bhh  = (const float*)d_in[9];
    const float* Wfc  = (const float*)d_in[10];
    const float* bfc  = (const float*)d_in[11];

    float* ws = (float*)d_ws;
    float* Wc   = ws;                              // 64*384
    float* bc   = Wc + GG*384;                     // 1024 (384 used)
    float* AXe  = bc + 1024;                       // 2 partials x 384 x 2048
    float* AXd  = AXe + (size_t)2*384*NN;          // 2 partials x 128 x 2048
    _Float16* Ah    = (_Float16*)(AXd + (size_t)2*128*NN);  // 2048x2048 (8 MB)
    _Float16* Xeh   = Ah    + (size_t)NN*NN;       // 384 x 2048
    _Float16* Xdh   = Xeh   + (size_t)384*NN;      // 128 x 2048
    _Float16* Hgh   = Xdh   + (size_t)128*NN;      // 12288 x 2048 (48 MB)
    _Float16* Z16   = Hgh   + (size_t)12288*NN;    // 2048 x 24576 (96 MB)
    _Float16* H16   = Z16   + (size_t)NN*24576;    // RR*HH fp16 (16 MB) master
    _Float16* Wcomb = H16   + (size_t)RR*HH;       // 384*192
    // decoder split-K ax partials (8 x 128 x 2048 fl = 8 MB) reuse the
    // AXe+AXd region (exactly 2*384*2048 + 2*128*2048 = 2097152 floats),
    // which is dead once the encoder consumed it.
    float* AXd8 = AXe;

    // Determinism insurance: zero the entire used workspace every call so
    // each call's output is a pure function of the inputs (the harness
    // re-poisons d_ws between verify and timing; post-timing check is a
    // consistency tripwire at 3.1x verify absmax).
    {
        size_t used = (size_t)((char*)(Wcomb + (size_t)384*192) - (char*)d_ws);
        hipMemsetAsync(d_ws, 0, used, stream);
    }

    cvtadj<<<2048, 256, 0, stream>>>(adj, Ah);
    wprep<<<98, 256, 0, stream>>>(Wg2, Wih, bih, bg2, Wc, bc);
    wprep2<<<288, 256, 0, stream>>>(Wc, Whh, Wcomb);
    xcvt_enc<<<384, 256, 0, stream>>>(x, Xeh);
    // encoder ax = adj @ Xe^T, all 12 steps (split-K 2, transposed fp32 C)
    gemm_mfma_T<<<dim3(3, 16, 2), 256, 0, stream>>>(
        Ah, Xeh, AXe, 1024, (size_t)384*NN);

    float* outp = (float*)d_out;

    // encoder z for all 12 steps: 2 groups of 6 (N=12288 cols each),
    // 256x384 BK=32 GEMM: 256 blocks = exactly 1 block/CU, 64 K-tiles
    for (int g = 0; g < 2; ++g) {
        h1T<<<dim3(NN, 6), 256, 0, stream>>>(
            AXe, g*192, (size_t)384*NN, Wg1, bg1, Hgh, 2);
        gemm384<<<256, 512, 0, stream>>>(
            Ah, Hgh, Z16 + (size_t)g*12288, 24576, 2048);
    }
    // ALL 12 encoder GRU steps fused; H stays in LDS/registers
    grufuse<<<RR/32, 512, 0, stream>>>(Z16, Wcomb, bc, bhh, H16);

    // decoder
    for (int p = 0; p < PP; ++p) {
        fck<<<RR/4, 256, 0, stream>>>(H16, Wfc, bfc, outp + (size_t)p*NN, Xdh);
        if (p < PP-1) {
            // ax = adj @ Xdh^T, split-K 8 (128 blocks vs 32) into AXe+AXd
            gemm_mfma_T<<<dim3(1, 16, 8), 256, 0, stream>>>(
                Ah, Xdh, AXd8, 256, (size_t)128*NN);
            h1T<<<dim3(NN, 1), 256, 0, stream>>>(
                AXd8, 0, (size_t)128*NN, Wg1, bg1, Hgh, 8);
            // decoder z: single-pass pipelined GEMM, fp16 direct into Z16
            // (replaces split-K gemm_mfma_p + zsum)
            gemmdz<<<dim3(16, 16), 256, 0, stream>>>(Ah, Hgh, Z16, 2048);
            gatemm2<0><<<256, 512, 0, stream>>>(
                Z16, 2048, 0, Wcomb, bc, bhh, H16);
        }
    }
}